// Round 11
// baseline (148.911 us; speedup 1.0000x reference)
//
#include <hip/hip_runtime.h>
#include <cstdint>
#include <math.h>

// SoftmaxGaussian: out_mean/out_var over 10000 MC softmax samples with
// JAX threefry2x32-exact random draw (key(42), shape (512,16,10000)).
//
// Layout facts:
//   N = 512*16*10000 ; half = 40,960,000 = 256*16*10000
//   flat j=(b*16+k)*10000+s ; threefry block i: counters (i, i+half),
//   key (0,42) -> (z[j=i], z[j=i+half]) => one call yields (b,k,s) AND
//   (b+256,k,s).
//
// R11: instruction cuts are dry (~1%/10% cut) and extra waves don't help
// (R7/R9); the one unexplained 20% lever is block GRANULARITY (R4->R6:
// 512->256 thr, same VGPR/waves/CU, 213->171 us). Extend it to its limit:
// 64-thread single-wave blocks. No inter-wave barriers, no LDS cross-wave
// epilogue (lane0 writes wave-reduced partials straight to ws), 4096
// uniform blocks = 16 blocks/CU x 1 wave = 16 waves/CU (same residency as
// R6). Inner loop bit-identical to R10. Fallback chain by ws_size:
// 64thr/NCH=16 (1MiB) -> 128thr/NCH=8 (512KiB) -> 256thr/NCH=4 (R10) ->
// single kernel.

typedef float f32x2 __attribute__((ext_vector_type(2)));

#define NSAMP 10000
#define HALF_N 40960000u

#define LOG2E 1.44269504088896340736f
#define NLN2 -0.69314718055994530942f
#define SQRT_LN2 0.83255461115769775635f
#define TAIL_TH -7.2134752f  // -5/ln2: main path iff l = log2(1-x^2) > this

__device__ __forceinline__ uint32_t rotl32(uint32_t x, int r) {
    return __builtin_rotateleft32(x, (unsigned)r);  // v_alignbit_b32
}

// JAX threefry2x32, key = (0, 42)
__device__ __forceinline__ void tf2x32(uint32_t x0, uint32_t x1,
                                       uint32_t& o0, uint32_t& o1) {
    const uint32_t ks1 = 42u;
    const uint32_t ks2 = 0x1BD11BDAu ^ 42u;
    x1 += ks1;
#define TF_R(r) { x0 += x1; x1 = rotl32(x1, r); x1 ^= x0; }
    TF_R(13) TF_R(15) TF_R(26) TF_R(6)   x0 += ks1; x1 += ks2 + 1u;
    TF_R(17) TF_R(29) TF_R(16) TF_R(24)  x0 += ks2; x1 += 2u;
    TF_R(13) TF_R(15) TF_R(26) TF_R(6)                x1 += ks1 + 3u;
    TF_R(17) TF_R(29) TF_R(16) TF_R(24)  x0 += ks1; x1 += ks2 + 4u;
    TF_R(13) TF_R(15) TF_R(26) TF_R(6)   x0 += ks2; x1 += 5u;
#undef TF_R
    o0 = x0;
    o1 = x1;
}

// JAX uniform(lo=nextafter(-1,0), hi=1), packed pair; one rounding (= JAX).
__device__ __forceinline__ f32x2 u2_from_bits(uint32_t ba, uint32_t bb) {
    f32x2 f;
    f.x = __uint_as_float((ba >> 9) | 0x3F800000u);
    f.y = __uint_as_float((bb >> 9) | 0x3F800000u);
    f = f - (f32x2){1.0f, 1.0f};  // exact (Sterbenz)
    return __builtin_elementwise_fma(f, (f32x2){2.0f, 2.0f},
                                     (f32x2){-0.99999994f, -0.99999994f});
}

// XLA's ErfInv f32 (Giles 2012), packed pair, wave-uniform tail skip.
// Values identical to the branchless version.
__device__ __forceinline__ f32x2 erfinv2(f32x2 x) {
    f32x2 t = __builtin_elementwise_fma(-x, x, (f32x2){1.0f, 1.0f});
    f32x2 l;
    l.x = __builtin_amdgcn_logf(t.x);
    l.y = __builtin_amdgcn_logf(t.y);
    f32x2 wm = __builtin_elementwise_fma((f32x2){NLN2, NLN2}, l,
                                         (f32x2){-2.5f, -2.5f});
#define P9(P, W, C) P = __builtin_elementwise_fma(P, W, (f32x2){C, C});
    f32x2 p1 = {2.81022636e-08f, 2.81022636e-08f};
    P9(p1, wm, 3.43273939e-07f)
    P9(p1, wm, -3.5233877e-06f)
    P9(p1, wm, -4.39150654e-06f)
    P9(p1, wm, 0.00021858087f)
    P9(p1, wm, -0.00125372503f)
    P9(p1, wm, -0.00417768164f)
    P9(p1, wm, 0.246640727f)
    P9(p1, wm, 1.50140941f)
    f32x2 p = p1;
    if (__any((l.x < TAIL_TH) || (l.y < TAIL_TH))) {
        f32x2 sq;
        sq.x = __builtin_amdgcn_sqrtf(-l.x);
        sq.y = __builtin_amdgcn_sqrtf(-l.y);
        f32x2 wt = __builtin_elementwise_fma((f32x2){SQRT_LN2, SQRT_LN2}, sq,
                                             (f32x2){-3.0f, -3.0f});
        f32x2 p2 = {-0.000200214257f, -0.000200214257f};
        P9(p2, wt, 0.000100950558f)
        P9(p2, wt, 0.00134934322f)
        P9(p2, wt, -0.00367342844f)
        P9(p2, wt, 0.00573950773f)
        P9(p2, wt, -0.0076224613f)
        P9(p2, wt, 0.00943887047f)
        P9(p2, wt, 1.00167406f)
        P9(p2, wt, 2.83297682f)
        p.x = (l.x > TAIL_TH) ? p1.x : p2.x;
        p.y = (l.y > TAIL_TH) ? p1.y : p2.y;
    }
#undef P9
    return p * x;
}

__device__ __forceinline__ float wave_sum(float v) {  // epilogue only
    v += __shfl_down(v, 32);
    v += __shfl_down(v, 16);
    v += __shfl_down(v, 8);
    v += __shfl_down(v, 4);
    v += __shfl_down(v, 2);
    v += __shfl_down(v, 1);
    return v;
}

// Partial kernel: block handles batch-row b (and b+256), samples
// [chunk*(NSAMP/NCH), ...). Writes 64 partials {s0,q0,s1,q1} per k to ws.
// Softmax in log2 domain (s_mu/s_sv pre-scaled by log2e), no max-subtract
// (|x| <= ~15: exp2 overflow-safe). Single-wave blocks (THR=64) skip the
// LDS cross-wave reduction entirely.
template <int THR, int NCH>
__global__ __launch_bounds__(THR, 2)
void sg_partial(const float* __restrict__ mean, const float* __restrict__ var,
                float* __restrict__ ws) {
    constexpr int W = THR / 64;
    __shared__ __attribute__((aligned(8))) float s_mu[2][16];
    __shared__ __attribute__((aligned(8))) float s_sv[2][16];
    __shared__ float s_red[W * 64];

    const int tid = threadIdx.x;
    const int b = blockIdx.x / NCH;
    const int chunk = blockIdx.x % NCH;
    const int s_begin = chunk * (NSAMP / NCH);
    const int s_end = s_begin + (NSAMP / NCH);

    if (tid < 32) {
        int h = tid >> 4, k = tid & 15;
        int bg = b + 256 * h;
        s_mu[h][k] = LOG2E * mean[bg * 16 + k];
        s_sv[h][k] = (LOG2E * 1.41421356237309515f) * sqrtf(var[bg * 16 + k]);
    }
    __syncthreads();

    f32x2 accs0[8], accq0[8], accs1[8], accq1[8];
#pragma unroll
    for (int kp = 0; kp < 8; kp++) {
        accs0[kp] = (f32x2){0.f, 0.f}; accq0[kp] = (f32x2){0.f, 0.f};
        accs1[kp] = (f32x2){0.f, 0.f}; accq1[kp] = (f32x2){0.f, 0.f};
    }

    const uint32_t base_bk = (uint32_t)(b * 16) * 10000u;

    for (int s = s_begin + tid; s < s_end; s += THR) {
        f32x2 e0[8], e1[8];
#pragma unroll
        for (int kp = 0; kp < 8; kp++) {
            uint32_t ia = base_bk + (uint32_t)(kp * 20000) + (uint32_t)s;
            uint32_t ib = ia + 10000u;
            uint32_t a0, a1, b0, b1;
            tf2x32(ia, ia + HALF_N, a0, a1);
            tf2x32(ib, ib + HALF_N, b0, b1);
            f32x2 z0 = erfinv2(u2_from_bits(a0, b0));  // batch b,     k pair
            f32x2 z1 = erfinv2(u2_from_bits(a1, b1));  // batch b+256, k pair
            f32x2 mu0 = *(const f32x2*)&s_mu[0][2 * kp];
            f32x2 sv0 = *(const f32x2*)&s_sv[0][2 * kp];
            f32x2 mu1 = *(const f32x2*)&s_mu[1][2 * kp];
            f32x2 sv1 = *(const f32x2*)&s_sv[1][2 * kp];
            e0[kp] = __builtin_elementwise_fma(z0, sv0, mu0);
            e1[kp] = __builtin_elementwise_fma(z1, sv1, mu1);
        }
        f32x2 sm0 = {0.f, 0.f}, sm1 = {0.f, 0.f};
#pragma unroll
        for (int kp = 0; kp < 8; kp++) {
            f32x2 t0, t1;
            t0.x = __builtin_amdgcn_exp2f(e0[kp].x);
            t0.y = __builtin_amdgcn_exp2f(e0[kp].y);
            t1.x = __builtin_amdgcn_exp2f(e1[kp].x);
            t1.y = __builtin_amdgcn_exp2f(e1[kp].y);
            e0[kp] = t0; sm0 += t0;
            e1[kp] = t1; sm1 += t1;
        }
        float inv0 = __builtin_amdgcn_rcpf(sm0.x + sm0.y);
        float inv1 = __builtin_amdgcn_rcpf(sm1.x + sm1.y);
        f32x2 iv0 = {inv0, inv0}, iv1 = {inv1, inv1};
#pragma unroll
        for (int kp = 0; kp < 8; kp++) {
            f32x2 p0 = e0[kp] * iv0;
            f32x2 p1 = e1[kp] * iv1;
            accs0[kp] += p0;
            accq0[kp] = __builtin_elementwise_fma(p0, p0, accq0[kp]);
            accs1[kp] += p1;
            accq1[kp] = __builtin_elementwise_fma(p1, p1, accq1[kp]);
        }
    }

    const int lane = tid & 63, wave = tid >> 6;
    float* wsb = ws + blockIdx.x * 64;
#pragma unroll
    for (int kp = 0; kp < 8; kp++) {
#define RED(val, slot) { \
        float r_ = wave_sum(val); \
        if (lane == 0) { \
            if constexpr (W == 1) wsb[(slot)] = r_; \
            else s_red[wave * 64 + (slot)] = r_; \
        } }
        RED(accs0[kp].x, (2 * kp) * 4 + 0)
        RED(accq0[kp].x, (2 * kp) * 4 + 1)
        RED(accs1[kp].x, (2 * kp) * 4 + 2)
        RED(accq1[kp].x, (2 * kp) * 4 + 3)
        RED(accs0[kp].y, (2 * kp + 1) * 4 + 0)
        RED(accq0[kp].y, (2 * kp + 1) * 4 + 1)
        RED(accs1[kp].y, (2 * kp + 1) * 4 + 2)
        RED(accq1[kp].y, (2 * kp + 1) * 4 + 3)
#undef RED
    }
    if constexpr (W > 1) {
        __syncthreads();
        if (tid < 64) {
            float t = 0.f;
#pragma unroll
            for (int w = 0; w < W; w++) t += s_red[w * 64 + tid];
            wsb[tid] = t;
        }
    }
}

__global__ __launch_bounds__(256)
void sg_finalize(const float* __restrict__ ws, float* __restrict__ out, int nch) {
    int t = blockIdx.x * blockDim.x + threadIdx.x;  // 0..8191
    if (t >= 8192) return;
    int k = t & 15, h = (t >> 4) & 1, b = t >> 5;
    float sum = 0.f, sq = 0.f;
    for (int c = 0; c < nch; c++) {
        const float* p = ws + ((b * nch + c) * 64 + k * 4 + 2 * h);
        sum += p[0];
        sq += p[1];
    }
    float mu = sum * (1.0f / 10000.0f);
    float vr = (sq - sum * mu) * (1.0f / 9999.0f);  // unbiased
    int bg = b + 256 * h;
    out[bg * 16 + k] = mu;
    out[8192 + bg * 16 + k] = vr;
}

// ---- fallback (ws too small): single kernel writes out directly ----
__global__ __launch_bounds__(256, 2)
void sg_kernel(const float* __restrict__ mean, const float* __restrict__ var,
               float* __restrict__ out) {
    // reuse the partial body via LDS staging of the 64 partials
    __shared__ float s_fin[64];
    // one block per b, full sample range; emulate by calling the 256-thr
    // partial logic inline would duplicate code — simplest correct path:
    // grid 256, each block accumulates all 10000 samples (as R10 fallback).
    constexpr int THR = 256;
    constexpr int W = THR / 64;
    __shared__ __attribute__((aligned(8))) float s_mu[2][16];
    __shared__ __attribute__((aligned(8))) float s_sv[2][16];
    __shared__ float s_red[W * 64];
    const int tid = threadIdx.x;
    const int b = blockIdx.x;
    if (tid < 32) {
        int h = tid >> 4, k = tid & 15;
        int bg = b + 256 * h;
        s_mu[h][k] = LOG2E * mean[bg * 16 + k];
        s_sv[h][k] = (LOG2E * 1.41421356237309515f) * sqrtf(var[bg * 16 + k]);
    }
    __syncthreads();
    f32x2 accs0[8], accq0[8], accs1[8], accq1[8];
#pragma unroll
    for (int kp = 0; kp < 8; kp++) {
        accs0[kp] = (f32x2){0.f, 0.f}; accq0[kp] = (f32x2){0.f, 0.f};
        accs1[kp] = (f32x2){0.f, 0.f}; accq1[kp] = (f32x2){0.f, 0.f};
    }
    const uint32_t base_bk = (uint32_t)(b * 16) * 10000u;
    for (int s = tid; s < NSAMP; s += THR) {
        f32x2 e0[8], e1[8];
#pragma unroll
        for (int kp = 0; kp < 8; kp++) {
            uint32_t ia = base_bk + (uint32_t)(kp * 20000) + (uint32_t)s;
            uint32_t ib = ia + 10000u;
            uint32_t a0, a1, b0, b1;
            tf2x32(ia, ia + HALF_N, a0, a1);
            tf2x32(ib, ib + HALF_N, b0, b1);
            f32x2 z0 = erfinv2(u2_from_bits(a0, b0));
            f32x2 z1 = erfinv2(u2_from_bits(a1, b1));
            e0[kp] = __builtin_elementwise_fma(z0, *(const f32x2*)&s_sv[0][2 * kp],
                                               *(const f32x2*)&s_mu[0][2 * kp]);
            e1[kp] = __builtin_elementwise_fma(z1, *(const f32x2*)&s_sv[1][2 * kp],
                                               *(const f32x2*)&s_mu[1][2 * kp]);
        }
        f32x2 sm0 = {0.f, 0.f}, sm1 = {0.f, 0.f};
#pragma unroll
        for (int kp = 0; kp < 8; kp++) {
            f32x2 t0, t1;
            t0.x = __builtin_amdgcn_exp2f(e0[kp].x);
            t0.y = __builtin_amdgcn_exp2f(e0[kp].y);
            t1.x = __builtin_amdgcn_exp2f(e1[kp].x);
            t1.y = __builtin_amdgcn_exp2f(e1[kp].y);
            e0[kp] = t0; sm0 += t0;
            e1[kp] = t1; sm1 += t1;
        }
        float inv0 = __builtin_amdgcn_rcpf(sm0.x + sm0.y);
        float inv1 = __builtin_amdgcn_rcpf(sm1.x + sm1.y);
        f32x2 iv0 = {inv0, inv0}, iv1 = {inv1, inv1};
#pragma unroll
        for (int kp = 0; kp < 8; kp++) {
            f32x2 p0 = e0[kp] * iv0;
            f32x2 p1 = e1[kp] * iv1;
            accs0[kp] += p0; accq0[kp] = __builtin_elementwise_fma(p0, p0, accq0[kp]);
            accs1[kp] += p1; accq1[kp] = __builtin_elementwise_fma(p1, p1, accq1[kp]);
        }
    }
    const int lane = tid & 63, wave = tid >> 6;
#pragma unroll
    for (int kp = 0; kp < 8; kp++) {
#define RED(val, slot) { float r_ = wave_sum(val); if (lane == 0) s_red[wave * 64 + (slot)] = r_; }
        RED(accs0[kp].x, (2 * kp) * 4 + 0)
        RED(accq0[kp].x, (2 * kp) * 4 + 1)
        RED(accs1[kp].x, (2 * kp) * 4 + 2)
        RED(accq1[kp].x, (2 * kp) * 4 + 3)
        RED(accs0[kp].y, (2 * kp + 1) * 4 + 0)
        RED(accq0[kp].y, (2 * kp + 1) * 4 + 1)
        RED(accs1[kp].y, (2 * kp + 1) * 4 + 2)
        RED(accq1[kp].y, (2 * kp + 1) * 4 + 3)
#undef RED
    }
    __syncthreads();
    if (tid < 64) {
        float t = 0.f;
#pragma unroll
        for (int w = 0; w < W; w++) t += s_red[w * 64 + tid];
        s_fin[tid] = t;
    }
    __syncthreads();
    if (tid < 32) {
        int h = tid >> 4, k = tid & 15;
        float sum = s_fin[k * 4 + 2 * h + 0];
        float sq  = s_fin[k * 4 + 2 * h + 1];
        float mu = sum * (1.0f / 10000.0f);
        float vr = (sq - sum * mu) * (1.0f / 9999.0f);
        int bg = b + 256 * h;
        out[bg * 16 + k] = mu;
        out[8192 + bg * 16 + k] = vr;
    }
}

extern "C" void kernel_launch(void* const* d_in, const int* in_sizes, int n_in,
                              void* d_out, int out_size, void* d_ws, size_t ws_size,
                              hipStream_t stream) {
    const float* mean = (const float*)d_in[0];
    const float* var  = (const float*)d_in[1];
    float* out = (float*)d_out;
    float* ws = (float*)d_ws;
    if (ws_size >= (size_t)256 * 16 * 64 * sizeof(float)) {        // 1 MiB
        sg_partial<64, 16><<<256 * 16, 64, 0, stream>>>(mean, var, ws);
        sg_finalize<<<32, 256, 0, stream>>>(ws, out, 16);
    } else if (ws_size >= (size_t)256 * 8 * 64 * sizeof(float)) {  // 512 KiB
        sg_partial<128, 8><<<256 * 8, 128, 0, stream>>>(mean, var, ws);
        sg_finalize<<<32, 256, 0, stream>>>(ws, out, 8);
    } else if (ws_size >= (size_t)256 * 4 * 64 * sizeof(float)) {  // 256 KiB
        sg_partial<256, 4><<<256 * 4, 256, 0, stream>>>(mean, var, ws);
        sg_finalize<<<32, 256, 0, stream>>>(ws, out, 4);
    } else {
        sg_kernel<<<256, 256, 0, stream>>>(mean, var, out);
    }
}